// Round 1
// 378.409 us; speedup vs baseline: 1.0116x; 1.0116x over previous
//
#include <hip/hip_runtime.h>
#include <hip/hip_bf16.h>
#include <hip/hip_fp16.h>

// ---------------------------------------------------------------------------
// GNN: h = relu(GCN(x)); h = relu(GAT(h)); h = relu(GCN(h)); h = relu(GAT(h));
//      z = h @ Wo + bo.  Outputs: [h (N*128), z (N*64)] fp32.
// R9: GEMM re-blocked for occupancy. R8 used 128 rows/block -> 391 blocks =
//     1.5 blocks/CU (latency-bound, 2-round imbalance, ~28 us each). Now one
//     16-row m-tile per wave, 64 rows per 256-thread block -> 782 blocks,
//     ~12 waves/CU. Wt is stored FRAGMENT-MAJOR by k_wcvt (each (nt,ks)
//     16x32 B-fragment contiguous: elem ((nt*4+ks)*64+lane)*8+j), so LDS
//     staging is a linear 32KB copy and B-frag ds_read_b128 is conflict-free
//     without padding. MFMA order/operands identical to R8 -> bit-identical
//     numerics. Build (R7 bucket sort) and agg (R6 pipelined gather) unchanged.
// ---------------------------------------------------------------------------

#define WAVE 64
#define BK 256        // nodes per bucket
#define CHUNK 4096    // edges per k_bscatter block

typedef _Float16 f16x8 __attribute__((ext_vector_type(8)));
typedef float f32x4 __attribute__((ext_vector_type(4)));

__global__ void k_zero_i32(int* __restrict__ p, int n) {
    int i = blockIdx.x * 256 + threadIdx.x;
    if (i < n) p[i] = 0;
}

// ------------------------------ graph build --------------------------------
// edge e in [0,E): (s,d) = (ei[e], ei[E+e]); e in [E,Et): self-loop (e-E,e-E)

__global__ __launch_bounds__(256) void k_bhist(
    const int* __restrict__ ei, int* __restrict__ bcnt,
    int E, int Et, int nbuck) {
    __shared__ int hist[256];
    int tid = threadIdx.x;
    if (tid < nbuck) hist[tid] = 0;
    __syncthreads();
    for (int e = blockIdx.x * 256 + tid; e < Et; e += gridDim.x * 256) {
        int d = (e < E) ? ei[E + e] : (e - E);
        atomicAdd(&hist[d >> 8], 1);
    }
    __syncthreads();
    if (tid < nbuck && hist[tid] > 0) atomicAdd(&bcnt[tid], hist[tid]);
}

__global__ void k_bscan(const int* __restrict__ bcnt, int* __restrict__ bbase,
                        int* __restrict__ bcur, int nbuck) {
    __shared__ int tmp[256];
    int tid = threadIdx.x;
    int v = (tid < nbuck) ? bcnt[tid] : 0;
    tmp[tid] = v;
    __syncthreads();
    for (int off = 1; off < 256; off <<= 1) {
        int t = (tid >= off) ? tmp[tid - off] : 0;
        __syncthreads();
        tmp[tid] += t;
        __syncthreads();
    }
    if (tid < nbuck) {
        int excl = tmp[tid] - v;
        bbase[tid] = excl;
        bcur[tid] = excl;
        if (tid == nbuck - 1) bbase[nbuck] = tmp[tid];
    }
}

__global__ __launch_bounds__(256) void k_bscatter(
    const int* __restrict__ ei, int* __restrict__ bcur,
    int2* __restrict__ ebuf, int E, int Et, int nbuck) {
    __shared__ int hist[256];
    __shared__ int base[256];
    __shared__ int off[256];
    constexpr int PT = CHUNK / 256;   // 16 edges per thread
    int tid = threadIdx.x;
    int cb = blockIdx.x * CHUNK;
    if (tid < nbuck) { hist[tid] = 0; off[tid] = 0; }
    __syncthreads();

    int sv[PT], dv[PT];
#pragma unroll
    for (int i = 0; i < PT; ++i) {
        int e = cb + i * 256 + tid;
        int s = 0, d = -1;
        if (e < Et) {
            if (e < E) { s = ei[e]; d = ei[E + e]; }
            else       { s = d = e - E; }
            atomicAdd(&hist[d >> 8], 1);
        }
        sv[i] = s; dv[i] = d;
    }
    __syncthreads();
    if (tid < nbuck && hist[tid] > 0)
        base[tid] = atomicAdd(&bcur[tid], hist[tid]);
    __syncthreads();
#pragma unroll
    for (int i = 0; i < PT; ++i) {
        if (dv[i] >= 0) {
            int b = dv[i] >> 8;
            int pos = base[b] + atomicAdd(&off[b], 1);
            ebuf[pos] = make_int2(sv[i], dv[i]);
        }
    }
}

__global__ __launch_bounds__(256) void k_csr(
    const int2* __restrict__ ebuf, const int* __restrict__ bbase,
    int* __restrict__ rowp, float* __restrict__ inv, int* __restrict__ esrc,
    int Nn, int Et) {
    __shared__ int hist[256];
    __shared__ int scan[256];
    __shared__ int cur[256];
    int tid = threadIdx.x;
    int b = blockIdx.x;
    int bb = bbase[b], cnt = bbase[b + 1] - bb;
    hist[tid] = 0;
    __syncthreads();
    for (int t = tid; t < cnt; t += 256)
        atomicAdd(&hist[ebuf[bb + t].y & 255], 1);
    __syncthreads();
    int v = hist[tid];
    scan[tid] = v;
    __syncthreads();
    for (int o = 1; o < 256; o <<= 1) {
        int t = (tid >= o) ? scan[tid - o] : 0;
        __syncthreads();
        scan[tid] += t;
        __syncthreads();
    }
    int excl = scan[tid] - v;
    int node = b * BK + tid;
    if (node < Nn) {
        rowp[node] = bb + excl;
        inv[node] = rsqrtf((float)v);
    }
    cur[tid] = excl;
    if (b == 0 && tid == 0) rowp[Nn] = Et;
    __syncthreads();
    for (int t = tid; t < cnt; t += 256) {
        int2 e = ebuf[bb + t];
        int pos = bb + atomicAdd(&cur[e.y & 255], 1);
        esrc[pos] = e.x;
    }
}

// -------------------- weight convert (fp32 -> fp16, fragment-major) --------
// Wt layout: [0]W1 [16384]Wg1 [32768]W2 [49152]Wg2 [65536]Wo
// Within each weight, B-fragments stored contiguously:
//   elem ((nt*4 + ks)*64 + lane)*8 + j  =  W[k][n]
//   with n = nt*16 + (lane&15), k = ks*32 + (lane>>4)*8 + j.
// This makes LDS staging a linear copy and B-frag reads conflict-free.

__global__ void k_wcvt(const float* __restrict__ W1, const float* __restrict__ Wg1,
                       const float* __restrict__ W2, const float* __restrict__ Wg2,
                       const float* __restrict__ Wo, __half* __restrict__ Wt) {
    int i = blockIdx.x * 256 + threadIdx.x;   // 73728 total
    if (i < 65536) {
        int w = i >> 14;
        int j = i & 16383;
        int nt = j >> 11, ks = (j >> 9) & 3, lane = (j >> 3) & 63, jj = j & 7;
        int n = nt * 16 + (lane & 15);
        int k = ks * 32 + (lane >> 4) * 8 + jj;
        const float* W = (w == 0) ? W1 : (w == 1) ? Wg1 : (w == 2) ? W2 : Wg2;
        Wt[i] = __float2half(W[k * 128 + n]);
    } else if (i < 73728) {
        int j = i - 65536;                    // 8192: Wo is 128x64 -> NT=4
        int nt = j >> 11, ks = (j >> 9) & 3, lane = (j >> 3) & 63, jj = j & 7;
        int n = nt * 16 + (lane & 15);
        int k = ks * 32 + (lane >> 4) * 8 + jj;
        Wt[65536 + j] = __float2half(Wo[k * 64 + n]);
    }
}

// ------------------------------ MFMA GEMM ----------------------------------
// out[M x NC] = A(fp32 M x 128) @ W(fp16, fragment-major Wt) ; fp32 accum.
// Block: 256 thr = 4 waves; each wave owns ONE 16-row m-tile -> 64 rows/block,
// 782 blocks (vs R8's 391x128 = 1.5 blocks/CU). W tile staged to LDS with a
// linear 16B-coalesced copy (fragment-major layout, no padding, no bank
// conflicts). Wave: NT n-tiles x 4 ksteps of mfma_f32_16x16x32_f16.
// A frag: lane m=lane&15, k=quad*8+j (dwordx4 x2 + cvt). C/D: col=lane&15,
// row=quad*4+reg. If asrc!=null, alpha logits reduced from fp32 accumulators.

template <int NC, typename OT>
__global__ __launch_bounds__(256) void gemm_mfma(
    const float* __restrict__ A, const __half* __restrict__ Wt,
    const float* __restrict__ bias, OT* __restrict__ out,
    const float* __restrict__ asrc, const float* __restrict__ adst,
    float* __restrict__ alS, float* __restrict__ alD, int M) {
    constexpr int NT = NC / 16;
    __shared__ f16x8 Wl[NC * 16];             // NC*128 halfs, fragment-major
    const int tid = threadIdx.x;
    const int wv = tid >> 6, lane = tid & 63;
    const int m16 = lane & 15, quad = lane >> 4;

    // linear staging: 16B per thread per iter, fully coalesced
#pragma unroll
    for (int i = tid; i < NC * 16; i += 256)
        Wl[i] = ((const f16x8*)Wt)[i];
    __syncthreads();

    const int row0 = blockIdx.x * 64 + wv * 16;

    f16x8 af[4];
    {
        int row = row0 + m16;
        if (row > M - 1) row = M - 1;
        const float* ap = A + (size_t)row * 128 + quad * 8;
#pragma unroll
        for (int ks = 0; ks < 4; ++ks) {
            float4 lo = *(const float4*)(ap + ks * 32);
            float4 hi = *(const float4*)(ap + ks * 32 + 4);
            f16x8 v;
            v[0] = (_Float16)lo.x; v[1] = (_Float16)lo.y;
            v[2] = (_Float16)lo.z; v[3] = (_Float16)lo.w;
            v[4] = (_Float16)hi.x; v[5] = (_Float16)hi.y;
            v[6] = (_Float16)hi.z; v[7] = (_Float16)hi.w;
            af[ks] = v;
        }
    }

    f32x4 acc[NT];
#pragma unroll
    for (int nt = 0; nt < NT; ++nt)
        acc[nt] = (f32x4){0.f, 0.f, 0.f, 0.f};

#pragma unroll
    for (int ks = 0; ks < 4; ++ks) {
#pragma unroll
        for (int nt = 0; nt < NT; ++nt) {
            f16x8 bf = Wl[(nt * 4 + ks) * 64 + lane];
            acc[nt] = __builtin_amdgcn_mfma_f32_16x16x32_f16(
                af[ks], bf, acc[nt], 0, 0, 0);
        }
    }

    // fused GAT alpha: s = xw.asrc, d = xw.adst per row (from fp32 accum)
    if (asrc) {
        float sa[NT], da[NT];
#pragma unroll
        for (int nt = 0; nt < NT; ++nt) {
            sa[nt] = asrc[nt * 16 + m16];
            da[nt] = adst[nt * 16 + m16];
        }
#pragma unroll
        for (int r = 0; r < 4; ++r) {
            float s = 0.f, d = 0.f;
#pragma unroll
            for (int nt = 0; nt < NT; ++nt) {
                s = fmaf(acc[nt][r], sa[nt], s);
                d = fmaf(acc[nt][r], da[nt], d);
            }
#pragma unroll
            for (int off = 8; off > 0; off >>= 1) {
                s += __shfl_xor(s, off);
                d += __shfl_xor(d, off);
            }
            int row = row0 + quad * 4 + r;
            if (m16 == 0 && row < M) { alS[row] = s; alD[row] = d; }
        }
    }

#pragma unroll
    for (int nt = 0; nt < NT; ++nt) {
#pragma unroll
        for (int r = 0; r < 4; ++r) {
            int row = row0 + quad * 4 + r;
            if (row < M) {
                float v = acc[nt][r];
                int col = nt * 16 + m16;
                if constexpr (sizeof(OT) == 2) {
                    ((__half*)out)[(size_t)row * NC + col] = __float2half(v);
                } else {
                    ((float*)out)[(size_t)row * NC + col] = v + bias[col];
                }
            }
        }
    }
}

// --------------------------- aggregation kernels ---------------------------
// One wave per destination node. lane = 16*g + q: quarter-wave g handles edge
// j+g of each group of 4; lane owns fp16 features 8q..8q+7 (16 B dwordx4).
// INVARIANT: lanes with index >= cnt hold wgt == 0 and a valid sid (0 ok);
// all 64 lanes active; every guard is wave-uniform so shfl always executes
// with full exec (R3 lesson: bpermute from inactive lane undefined).

__device__ __forceinline__ void gather_accum_h(
    const __half* __restrict__ xw, int q, int g, int cnt, int sid, float wgt,
    float acc[8]) {
    for (int base = 0; base < cnt; base += 32) {
        int c = cnt - base;           // wave-uniform
        float4 x[8];
        float w[8];
#pragma unroll
        for (int u = 0; u < 8; ++u) {
            if (u * 4 < c) {          // uniform guard
                int idx = base + 4 * u + g;
                int s = __shfl(sid, idx);
                w[u] = __shfl(wgt, idx);
                x[u] = *(const float4*)(xw + (size_t)s * 128 + q * 8);
            }
        }
#pragma unroll
        for (int u = 0; u < 8; ++u) {
            if (u * 4 < c) {          // uniform guard
                const __half2* h2 = (const __half2*)&x[u];
#pragma unroll
                for (int i = 0; i < 4; ++i) {
                    float2 cc = __half22float2(h2[i]);
                    acc[2 * i]     = fmaf(w[u], cc.x, acc[2 * i]);
                    acc[2 * i + 1] = fmaf(w[u], cc.y, acc[2 * i + 1]);
                }
            }
        }
    }
}

__device__ __forceinline__ void finish_store_q(
    float acc[8], const float* __restrict__ bias, float* __restrict__ out,
    int n, int q, int g) {
#pragma unroll
    for (int i = 0; i < 8; ++i) {
        acc[i] += __shfl_xor(acc[i], 16);
        acc[i] += __shfl_xor(acc[i], 32);
    }
    if (g == 0) {
        float4 b0 = ((const float4*)bias)[q * 2];
        float4 b1 = ((const float4*)bias)[q * 2 + 1];
        float4 r0, r1;
        r0.x = fmaxf(acc[0] + b0.x, 0.f);
        r0.y = fmaxf(acc[1] + b0.y, 0.f);
        r0.z = fmaxf(acc[2] + b0.z, 0.f);
        r0.w = fmaxf(acc[3] + b0.w, 0.f);
        r1.x = fmaxf(acc[4] + b1.x, 0.f);
        r1.y = fmaxf(acc[5] + b1.y, 0.f);
        r1.z = fmaxf(acc[6] + b1.z, 0.f);
        r1.w = fmaxf(acc[7] + b1.w, 0.f);
        float4* orow = (float4*)(out + (size_t)n * 128);
        orow[q * 2]     = r0;
        orow[q * 2 + 1] = r1;
    }
}

__global__ __launch_bounds__(256) void k_gcn_agg(
    const __half* __restrict__ xw, const int* __restrict__ rowp,
    const int* __restrict__ esrc, const float* __restrict__ inv,
    const float* __restrict__ bias, float* __restrict__ out, int Nn) {
    int gid = blockIdx.x * 256 + threadIdx.x;
    int n = gid >> 6, lane = gid & 63;
    if (n >= Nn) return;
    int q = lane & 15, g = lane >> 4;
    int beg = rowp[n], end = rowp[n + 1];
    float invd = inv[n];
    float acc[8] = {0.f, 0.f, 0.f, 0.f, 0.f, 0.f, 0.f, 0.f};
    for (int base = beg; base < end; base += WAVE) {
        int e = base + lane;
        bool valid = (e < end);
        int sid = valid ? esrc[e] : 0;
        float c = valid ? invd * inv[sid] : 0.f;
        gather_accum_h(xw, q, g, min(WAVE, end - base), sid, c, acc);
    }
    finish_store_q(acc, bias, out, n, q, g);
}

__global__ __launch_bounds__(256) void k_gat_agg(
    const __half* __restrict__ xw, const int* __restrict__ rowp,
    const int* __restrict__ esrc, const float* __restrict__ as_,
    const float* __restrict__ ad_, const float* __restrict__ bias,
    float* __restrict__ out, int Nn) {
    int gid = blockIdx.x * 256 + threadIdx.x;
    int n = gid >> 6, lane = gid & 63;
    if (n >= Nn) return;
    int q = lane & 15, g = lane >> 4;
    int beg = rowp[n], end = rowp[n + 1];
    int deg = end - beg;
    float adn = ad_[n];
    float acc[8] = {0.f, 0.f, 0.f, 0.f, 0.f, 0.f, 0.f, 0.f};

    if (deg <= WAVE) {
        // fused path (deg<=64, ~all nodes): edge data loaded once, logit in reg
        bool valid = (lane < deg);
        int sid = 0;
        float v = -1e30f;
        if (valid) {
            sid = esrc[beg + lane];
            float t = as_[sid] + adn;
            v = (t > 0.f) ? t : 0.2f * t;
        }
        float m = v;
#pragma unroll
        for (int off = 32; off > 0; off >>= 1) m = fmaxf(m, __shfl_xor(m, off));
        float ex = valid ? __expf(v - m) : 0.f;
        float ssum = ex;
#pragma unroll
        for (int off = 32; off > 0; off >>= 1) ssum += __shfl_xor(ssum, off);
        float wgt = ex * (1.f / ssum);   // invalid lanes: 0
        gather_accum_h(xw, q, g, deg, sid, wgt, acc);
    } else {
        // generic two-pass path (deg>64: essentially never at E/N=16)
        float m = -1e30f, ssum = 0.f;
        for (int e = beg + lane; e < end; e += WAVE) {
            float v = as_[esrc[e]] + adn;
            v = (v > 0.f) ? v : 0.2f * v;
            float mn = fmaxf(m, v);
            ssum = ssum * __expf(m - mn) + __expf(v - mn);
            m = mn;
        }
#pragma unroll
        for (int off = 32; off > 0; off >>= 1) {
            float mo = __shfl_xor(m, off);
            float so = __shfl_xor(ssum, off);
            float mn = fmaxf(m, mo);
            ssum = ssum * __expf(m - mn) + so * __expf(mo - mn);
            m = mn;
        }
        float rden = 1.f / ssum;
        for (int base = beg; base < end; base += WAVE) {
            int e = base + lane;
            bool valid = (e < end);
            int sid = valid ? esrc[e] : 0;
            float wgt = 0.f;
            if (valid) {
                float v = as_[sid] + adn;
                v = (v > 0.f) ? v : 0.2f * v;
                wgt = __expf(v - m) * rden;
            }
            gather_accum_h(xw, q, g, min(WAVE, end - base), sid, wgt, acc);
        }
    }
    finish_store_q(acc, bias, out, n, q, g);
}

// ------------------------------- launch ------------------------------------

extern "C" void kernel_launch(void* const* d_in, const int* in_sizes, int n_in,
                              void* d_out, int out_size, void* d_ws, size_t ws_size,
                              hipStream_t stream) {
    const float* x   = (const float*)d_in[0];
    const int*   ei  = (const int*)d_in[1];
    const float* W1  = (const float*)d_in[2];
    const float* b1  = (const float*)d_in[3];
    const float* Wg1 = (const float*)d_in[4];
    const float* as1 = (const float*)d_in[5];
    const float* ad1 = (const float*)d_in[6];
    const float* bg1 = (const float*)d_in[7];
    const float* W2  = (const float*)d_in[8];
    const float* b2  = (const float*)d_in[9];
    const float* Wg2 = (const float*)d_in[10];
    const float* as2 = (const float*)d_in[11];
    const float* ad2 = (const float*)d_in[12];
    const float* bg2 = (const float*)d_in[13];
    const float* Wo  = (const float*)d_in[14];
    const float* bo  = (const float*)d_in[15];

    const int Nn = in_sizes[0] / 128;
    const int E  = in_sizes[1] / 2;
    const int Et = E + Nn;
    const int H  = 128;
    const int nbuck = (Nn + BK - 1) / BK;   // 196

    float* outH = (float*)d_out;
    float* outZ = outH + (size_t)Nn * H;

    char* p = (char*)d_ws;
    auto carve = [&](size_t bytes) {
        char* r = p;
        p += (bytes + 255) & ~(size_t)255;
        return r;
    };
    __half* bufA = (__half*)carve((size_t)Nn * H * sizeof(__half));  // xw (fp16)
    __half* Wt   = (__half*)carve((size_t)73728 * sizeof(__half));   // fp16 W frags x5
    float* alS   = (float*)carve((size_t)Nn * sizeof(float));
    float* alD   = (float*)carve((size_t)Nn * sizeof(float));
    float* inv   = (float*)carve((size_t)Nn * sizeof(float));
    int*   rowp  = (int*)carve((size_t)(Nn + 1) * sizeof(int));
    int*   esrc  = (int*)carve((size_t)Et * sizeof(int));
    int2*  ebuf  = (int2*)carve((size_t)Et * sizeof(int2));
    int*   bcnt  = (int*)carve((size_t)nbuck * sizeof(int));
    int*   bbase = (int*)carve((size_t)(nbuck + 1) * sizeof(int));
    int*   bcur  = (int*)carve((size_t)nbuck * sizeof(int));
    (void)ws_size; (void)n_in; (void)out_size;

    const int aggBlocks = (Nn * WAVE + 255) / 256;
    const int gemmB = (Nn + 63) / 64;             // 782: ~3 blocks/CU
    const int scatB = (Et + CHUNK - 1) / CHUNK;   // 208

    // graph build (two-level bucket sort)
    k_zero_i32<<<1, 256, 0, stream>>>(bcnt, nbuck);
    k_bhist<<<104, 256, 0, stream>>>(ei, bcnt, E, Et, nbuck);
    k_bscan<<<1, 256, 0, stream>>>(bcnt, bbase, bcur, nbuck);
    k_bscatter<<<scatB, 256, 0, stream>>>(ei, bcur, ebuf, E, Et, nbuck);
    k_csr<<<nbuck, 256, 0, stream>>>(ebuf, bbase, rowp, inv, esrc, Nn, Et);
    k_wcvt<<<288, 256, 0, stream>>>(W1, Wg1, W2, Wg2, Wo, Wt);

    gemm_mfma<128, __half><<<gemmB, 256, 0, stream>>>(
        x, Wt, nullptr, bufA, nullptr, nullptr, nullptr, nullptr, Nn);
    k_gcn_agg<<<aggBlocks, 256, 0, stream>>>(bufA, rowp, esrc, inv, b1, outH, Nn);

    gemm_mfma<128, __half><<<gemmB, 256, 0, stream>>>(
        outH, Wt + 16384, nullptr, bufA, as1, ad1, alS, alD, Nn);
    k_gat_agg<<<aggBlocks, 256, 0, stream>>>(bufA, rowp, esrc, alS, alD, bg1, outH, Nn);

    gemm_mfma<128, __half><<<gemmB, 256, 0, stream>>>(
        outH, Wt + 32768, nullptr, bufA, nullptr, nullptr, nullptr, nullptr, Nn);
    k_gcn_agg<<<aggBlocks, 256, 0, stream>>>(bufA, rowp, esrc, inv, b2, outH, Nn);

    gemm_mfma<128, __half><<<gemmB, 256, 0, stream>>>(
        outH, Wt + 49152, nullptr, bufA, as2, ad2, alS, alD, Nn);
    k_gat_agg<<<aggBlocks, 256, 0, stream>>>(bufA, rowp, esrc, alS, alD, bg2, outH, Nn);

    gemm_mfma<64, float><<<gemmB, 256, 0, stream>>>(
        outH, Wt + 65536, bo, outZ, nullptr, nullptr, nullptr, nullptr, Nn);
}